// Round 3
// baseline (118.352 us; speedup 1.0000x reference)
//
#include <hip/hip_runtime.h>
#include <hip/hip_bf16.h>

// Problem constants
#define B_   32
#define LLT  1024
#define LRT  1024
#define H_   256
#define A_   128

typedef __attribute__((ext_vector_type(8))) short  short8;
typedef __attribute__((ext_vector_type(4))) short  short4v;
typedef __attribute__((ext_vector_type(4))) float  f32x4;
typedef __bf16 bf16x8 __attribute__((ext_vector_type(8)));

static __device__ __forceinline__ unsigned short f2bf(float f) {
    return __builtin_bit_cast(unsigned short, (__bf16)f);   // native cvt, RNE
}

static __device__ __forceinline__ bf16x8 ld_bf8(const unsigned short* p) {
    return __builtin_bit_cast(bf16x8, *reinterpret_cast<const short8*>(p));
}

// fast tanh: (e^2x - 1) / (e^2x + 1); rel err ~1e-6, far below bf16 rounding
static __device__ __forceinline__ float fast_tanh(float x) {
    float cx = fminf(fmaxf(x, -15.f), 15.f);
    float e  = __expf(2.f * cx);
    return (e - 1.f) * __builtin_amdgcn_rcpf(e + 1.f);
}

// ---------------------------------------------------------------------------
// Kernel 0: attn_kernel [H][A] f32  ->  Kt [A][H] bf16 (transposed for frags)
// ---------------------------------------------------------------------------
__global__ void k_prep(const float* __restrict__ K, unsigned short* __restrict__ Kt) {
    int i = blockIdx.x * 256 + threadIdx.x;       // i in [0, A_*H_)
    int a = i >> 8;                               // / H_
    int h = i & (H_ - 1);
    Kt[i] = f2bf(K[h * A_ + a]);
}

// ---------------------------------------------------------------------------
// Kernel A: projection  [32768,256] @ [256,128] -> tanh -> (*diagW) -> bf16
// grid (256, 2): x = 128-row tile, y = {lt, rt}. block = 256 (4 waves).
// SWAPPED MFMA: A = Kt fragment (proj cols), B = reps fragment (proj rows)
// => C: lane&15 = proj ROW, reg = 4 consecutive proj COLS  -> short4 stores.
// ---------------------------------------------------------------------------
__global__ __launch_bounds__(256) void k_proj(
        const float* __restrict__ reps_lt, const float* __restrict__ reps_rt,
        const unsigned short* __restrict__ Kt, const float* __restrict__ dW,
        unsigned short* __restrict__ lt_bf, unsigned short* __restrict__ rt_bf) {
    const bool is_lt = (blockIdx.y == 0);
    const float* __restrict__ src = is_lt ? reps_lt : reps_rt;
    unsigned short* __restrict__ dst = is_lt ? lt_bf : rt_bf;

    const int tid  = threadIdx.x;
    const int wave = tid >> 6, lane = tid & 63;
    const int g = lane >> 4, r0 = lane & 15;
    const int m0 = blockIdx.x * 128 + wave * 32;     // this wave's 32 rows

    f32x4 zero = {0.f, 0.f, 0.f, 0.f};
    f32x4 acc[8][2];                                  // [col-tile][row-tile]
    #pragma unroll
    for (int c = 0; c < 8; ++c) { acc[c][0] = zero; acc[c][1] = zero; }

    #pragma unroll
    for (int ks = 0; ks < 8; ++ks) {
        bf16x8 br[2];                                 // reps rows (B operand)
        #pragma unroll
        for (int mr = 0; mr < 2; ++mr) {
            const float* p = src + (size_t)(m0 + mr * 16 + r0) * H_ + ks * 32 + g * 8;
            float4 x0 = *reinterpret_cast<const float4*>(p);
            float4 x1 = *reinterpret_cast<const float4*>(p + 4);
            short8 t;
            t[0] = (short)f2bf(x0.x); t[1] = (short)f2bf(x0.y);
            t[2] = (short)f2bf(x0.z); t[3] = (short)f2bf(x0.w);
            t[4] = (short)f2bf(x1.x); t[5] = (short)f2bf(x1.y);
            t[6] = (short)f2bf(x1.z); t[7] = (short)f2bf(x1.w);
            br[mr] = __builtin_bit_cast(bf16x8, t);
        }
        #pragma unroll
        for (int c = 0; c < 8; ++c) {
            bf16x8 ka = ld_bf8(Kt + (size_t)(c * 16 + r0) * H_ + ks * 32 + g * 8);
            acc[c][0] = __builtin_amdgcn_mfma_f32_16x16x32_bf16(ka, br[0], acc[c][0], 0, 0, 0);
            acc[c][1] = __builtin_amdgcn_mfma_f32_16x16x32_bf16(ka, br[1], acc[c][1], 0, 0, 0);
        }
    }

    #pragma unroll
    for (int c = 0; c < 8; ++c) {
        f32x4 w4;
        if (is_lt) w4 = *reinterpret_cast<const f32x4*>(dW + c * 16 + 4 * g);
        else       { w4[0] = 1.f; w4[1] = 1.f; w4[2] = 1.f; w4[3] = 1.f; }
        #pragma unroll
        for (int mr = 0; mr < 2; ++mr) {
            int row = m0 + mr * 16 + r0;              // lane&15 = row now
            short4v o;
            #pragma unroll
            for (int r = 0; r < 4; ++r)
                o[r] = (short)f2bf(fast_tanh(acc[c][mr][r]) * w4[r]);
            *reinterpret_cast<short4v*>(dst + (size_t)row * A_ + c * 16 + 4 * g) = o;
        }
    }
}

// ---------------------------------------------------------------------------
// Kernel B: per (batch, 32-row tile): S = lt·rt^T (K=128), masks, softmax, store
// grid 1024 (1-D, XCD-grouped: each XCD owns 4 batches so rt stays in its L2).
// block = 512 (8 waves, 128 cols each).
// SWAPPED MFMA: A = rt frag (out cols), B = lt frag (out rows)
// => lane&15 = out ROW, reg = 4 consecutive out COLS -> float4 NT stores.
// ---------------------------------------------------------------------------
__global__ __launch_bounds__(512) void k_attn(
        const unsigned short* __restrict__ lt_bf, const unsigned short* __restrict__ rt_bf,
        const float* __restrict__ mask_lt, const float* __restrict__ mask_rt,
        float* __restrict__ out) {
    // XCD-aware decode: XCD = blk%8 (heuristic); XCD x serves batches 4x..4x+3.
    const int blk = blockIdx.x;
    const int b   = (blk & 7) * 4 + ((blk >> 3) & 3);
    const int m0  = (blk >> 5) * 32;

    const int tid = threadIdx.x;
    const int wave = tid >> 6, lane = tid & 63;
    const int g = lane >> 4, r0 = lane & 15;
    const int cb = wave * 128;

    const unsigned short* __restrict__ ltb = lt_bf + ((size_t)b * LLT + m0) * A_;
    const unsigned short* __restrict__ rtb = rt_bf + (size_t)b * LRT * A_;

    // lt fragments (B operand): 2 row-tiles x 4 k-steps
    bf16x8 lb[2][4];
    #pragma unroll
    for (int mr = 0; mr < 2; ++mr)
        #pragma unroll
        for (int ks = 0; ks < 4; ++ks)
            lb[mr][ks] = ld_bf8(ltb + (size_t)(mr * 16 + r0) * A_ + ks * 32 + g * 8);

    f32x4 zero = {0.f, 0.f, 0.f, 0.f};
    f32x4 acc[8][2];                                  // [col-tile][row-tile]
    #pragma unroll
    for (int c = 0; c < 8; ++c) { acc[c][0] = zero; acc[c][1] = zero; }

    #pragma unroll
    for (int c = 0; c < 8; ++c) {
        const unsigned short* rp = rtb + (size_t)(cb + c * 16 + r0) * A_;
        #pragma unroll
        for (int ks = 0; ks < 4; ++ks) {
            bf16x8 ra = ld_bf8(rp + ks * 32 + g * 8);   // rt rows = out cols (A operand)
            acc[c][0] = __builtin_amdgcn_mfma_f32_16x16x32_bf16(ra, lb[0][ks], acc[c][0], 0, 0, 0);
            acc[c][1] = __builtin_amdgcn_mfma_f32_16x16x32_bf16(ra, lb[1][ks], acc[c][1], 0, 0, 0);
        }
    }

    // masks: mask_rt as float4 per col-tile (cols cb+c*16+4g..+3), mask_lt per row
    float mlt[2];
    #pragma unroll
    for (int mr = 0; mr < 2; ++mr)
        mlt[mr] = mask_lt[(size_t)b * LLT + m0 + mr * 16 + r0];

    // exp (no max pass: |logit| <= ~20, clamp for safety) + per-row sums.
    // Fold mask_rt into stored P so mrt regs die before the store phase.
    __shared__ float red_sum[8][32];
    float rsum[2];
    #pragma unroll
    for (int mr = 0; mr < 2; ++mr) rsum[mr] = 0.f;

    #pragma unroll
    for (int c = 0; c < 8; ++c) {
        f32x4 m4 = *reinterpret_cast<const f32x4*>(mask_rt + (size_t)b * LRT + cb + c * 16 + 4 * g);
        #pragma unroll
        for (int mr = 0; mr < 2; ++mr)
            #pragma unroll
            for (int r = 0; r < 4; ++r) {
                float v = acc[c][mr][r] * (mlt[mr] * m4[r]);
                float e = __expf(fminf(v, 60.f));
                acc[c][mr][r] = e * m4[r];            // post-softmax rt-mask folded in
                rsum[mr] += e;
            }
    }
    #pragma unroll
    for (int mr = 0; mr < 2; ++mr) {
        float s = rsum[mr];
        s += __shfl_xor(s, 16, 64);
        s += __shfl_xor(s, 32, 64);
        rsum[mr] = s;
    }
    if (g == 0) {
        red_sum[wave][r0]      = rsum[0];
        red_sum[wave][16 + r0] = rsum[1];
    }
    __syncthreads();
    float sc[2];
    #pragma unroll
    for (int mr = 0; mr < 2; ++mr) {
        int rl = mr * 16 + r0;
        float s = red_sum[0][rl];
        #pragma unroll
        for (int w = 1; w < 8; ++w) s += red_sum[w][rl];
        sc[mr] = mlt[mr] * __builtin_amdgcn_rcpf(s);  // post-softmax lt-mask folded in
    }

    // store: float4 per (c, mr), non-temporal (write-once output)
    #pragma unroll
    for (int mr = 0; mr < 2; ++mr) {
        float* op = out + ((size_t)b * LLT + m0 + mr * 16 + r0) * LRT + cb;
        #pragma unroll
        for (int c = 0; c < 8; ++c) {
            f32x4 o;
            #pragma unroll
            for (int r = 0; r < 4; ++r) o[r] = acc[c][mr][r] * sc[mr];
            __builtin_nontemporal_store(o, reinterpret_cast<f32x4*>(op + c * 16 + 4 * g));
        }
    }
}

// ---------------------------------------------------------------------------
extern "C" void kernel_launch(void* const* d_in, const int* in_sizes, int n_in,
                              void* d_out, int out_size, void* d_ws, size_t ws_size,
                              hipStream_t stream) {
    const float* reps_lt = (const float*)d_in[0];
    const float* reps_rt = (const float*)d_in[1];
    const float* mask_lt = (const float*)d_in[2];
    const float* mask_rt = (const float*)d_in[3];
    const float* attn_k  = (const float*)d_in[4];
    const float* diagW   = (const float*)d_in[5];
    float* out = (float*)d_out;

    // workspace layout (bf16 as ushort bits)
    unsigned short* Kt  = (unsigned short*)d_ws;                // [A][H]   64 KB
    unsigned short* ltb = Kt + (size_t)A_ * H_;                 // [B*LLT][A]  8 MB
    unsigned short* rtb = ltb + (size_t)B_ * LLT * A_;          // [B*LRT][A]  8 MB

    k_prep<<<dim3((A_ * H_) / 256), dim3(256), 0, stream>>>(attn_k, Kt);
    k_proj<<<dim3((B_ * LLT) / 128, 2), dim3(256), 0, stream>>>(
        reps_lt, reps_rt, Kt, diagW, ltb, rtb);
    k_attn<<<dim3(LLT / 32 * B_), dim3(512), 0, stream>>>(
        ltb, rtb, mask_lt, mask_rt, out);
}

// Round 4
// 106.946 us; speedup vs baseline: 1.1067x; 1.1067x over previous
//
#include <hip/hip_runtime.h>
#include <hip/hip_bf16.h>

// Problem constants
#define B_   32
#define LLT  1024
#define LRT  1024
#define H_   256
#define A_   128

typedef __attribute__((ext_vector_type(8))) short  short8;
typedef __attribute__((ext_vector_type(4))) short  short4v;
typedef __attribute__((ext_vector_type(4))) float  f32x4;
typedef __bf16 bf16x8 __attribute__((ext_vector_type(8)));

static __device__ __forceinline__ unsigned short f2bf(float f) {
    return __builtin_bit_cast(unsigned short, (__bf16)f);   // native cvt, RNE
}

static __device__ __forceinline__ bf16x8 ld_bf8(const unsigned short* p) {
    return __builtin_bit_cast(bf16x8, *reinterpret_cast<const short8*>(p));
}

// fast tanh: (e^2x - 1) / (e^2x + 1); rel err ~1e-6, far below bf16 rounding
static __device__ __forceinline__ float fast_tanh(float x) {
    float cx = fminf(fmaxf(x, -15.f), 15.f);
    float e  = __expf(2.f * cx);
    return (e - 1.f) * __builtin_amdgcn_rcpf(e + 1.f);
}

// ---------------------------------------------------------------------------
// Kernel 0: attn_kernel [H][A] f32  ->  Kt [A][H] bf16 (transposed for frags)
// ---------------------------------------------------------------------------
__global__ void k_prep(const float* __restrict__ K, unsigned short* __restrict__ Kt) {
    int i = blockIdx.x * 256 + threadIdx.x;       // i in [0, A_*H_)
    int a = i >> 8;                               // / H_
    int h = i & (H_ - 1);
    Kt[i] = f2bf(K[h * A_ + a]);
}

// ---------------------------------------------------------------------------
// Kernel A: projection  [32768,256] @ [256,128] -> tanh -> (*diagW) -> bf16
// grid (256, 2): x = 128-row tile, y = {lt, rt}. block = 256 (4 waves).
// SWAPPED MFMA: A = Kt fragment (proj cols), B = reps fragment (proj rows)
// => C: lane&15 = proj ROW, reg = 4 consecutive proj COLS  -> short4 stores.
// ---------------------------------------------------------------------------
__global__ __launch_bounds__(256) void k_proj(
        const float* __restrict__ reps_lt, const float* __restrict__ reps_rt,
        const unsigned short* __restrict__ Kt, const float* __restrict__ dW,
        unsigned short* __restrict__ lt_bf, unsigned short* __restrict__ rt_bf) {
    const bool is_lt = (blockIdx.y == 0);
    const float* __restrict__ src = is_lt ? reps_lt : reps_rt;
    unsigned short* __restrict__ dst = is_lt ? lt_bf : rt_bf;

    const int tid  = threadIdx.x;
    const int wave = tid >> 6, lane = tid & 63;
    const int g = lane >> 4, r0 = lane & 15;
    const int m0 = blockIdx.x * 128 + wave * 32;     // this wave's 32 rows

    f32x4 zero = {0.f, 0.f, 0.f, 0.f};
    f32x4 acc[8][2];                                  // [col-tile][row-tile]
    #pragma unroll
    for (int c = 0; c < 8; ++c) { acc[c][0] = zero; acc[c][1] = zero; }

    #pragma unroll
    for (int ks = 0; ks < 8; ++ks) {
        bf16x8 br[2];                                 // reps rows (B operand)
        #pragma unroll
        for (int mr = 0; mr < 2; ++mr) {
            const float* p = src + (size_t)(m0 + mr * 16 + r0) * H_ + ks * 32 + g * 8;
            float4 x0 = *reinterpret_cast<const float4*>(p);
            float4 x1 = *reinterpret_cast<const float4*>(p + 4);
            short8 t;
            t[0] = (short)f2bf(x0.x); t[1] = (short)f2bf(x0.y);
            t[2] = (short)f2bf(x0.z); t[3] = (short)f2bf(x0.w);
            t[4] = (short)f2bf(x1.x); t[5] = (short)f2bf(x1.y);
            t[6] = (short)f2bf(x1.z); t[7] = (short)f2bf(x1.w);
            br[mr] = __builtin_bit_cast(bf16x8, t);
        }
        #pragma unroll
        for (int c = 0; c < 8; ++c) {
            bf16x8 ka = ld_bf8(Kt + (size_t)(c * 16 + r0) * H_ + ks * 32 + g * 8);
            acc[c][0] = __builtin_amdgcn_mfma_f32_16x16x32_bf16(ka, br[0], acc[c][0], 0, 0, 0);
            acc[c][1] = __builtin_amdgcn_mfma_f32_16x16x32_bf16(ka, br[1], acc[c][1], 0, 0, 0);
        }
    }

    #pragma unroll
    for (int c = 0; c < 8; ++c) {
        f32x4 w4;
        if (is_lt) w4 = *reinterpret_cast<const f32x4*>(dW + c * 16 + 4 * g);
        else       { w4[0] = 1.f; w4[1] = 1.f; w4[2] = 1.f; w4[3] = 1.f; }
        #pragma unroll
        for (int mr = 0; mr < 2; ++mr) {
            int row = m0 + mr * 16 + r0;              // lane&15 = row now
            short4v o;
            #pragma unroll
            for (int r = 0; r < 4; ++r)
                o[r] = (short)f2bf(fast_tanh(acc[c][mr][r]) * w4[r]);
            *reinterpret_cast<short4v*>(dst + (size_t)row * A_ + c * 16 + 4 * g) = o;
        }
    }
}

// ---------------------------------------------------------------------------
// Kernel B: per (batch, 32-row tile): S = lt·rt^T (K=128), masks, softmax, store
// grid 1024 (1-D, XCD-grouped: each XCD owns 4 batches so rt stays in its L2).
// block = 512 (8 waves, 128 cols each).
// SWAPPED MFMA: A = rt frag (out cols), B = lt frag (out rows)
// => lane&15 = out ROW, reg = 4 consecutive out COLS -> float4 stores.
// Stores go through L2 (NOT non-temporal): adjacent 64-B halves merge into
// full 128-B lines before writeback; NT bypass caused 1.46x write amp.
// ---------------------------------------------------------------------------
__global__ __launch_bounds__(512) void k_attn(
        const unsigned short* __restrict__ lt_bf, const unsigned short* __restrict__ rt_bf,
        const float* __restrict__ mask_lt, const float* __restrict__ mask_rt,
        float* __restrict__ out) {
    // XCD-aware decode: XCD = blk%8 (heuristic); XCD x serves batches 4x..4x+3.
    const int blk = blockIdx.x;
    const int b   = (blk & 7) * 4 + ((blk >> 3) & 3);
    const int m0  = (blk >> 5) * 32;

    const int tid = threadIdx.x;
    const int wave = tid >> 6, lane = tid & 63;
    const int g = lane >> 4, r0 = lane & 15;
    const int cb = wave * 128;

    const unsigned short* __restrict__ ltb = lt_bf + ((size_t)b * LLT + m0) * A_;
    const unsigned short* __restrict__ rtb = rt_bf + (size_t)b * LRT * A_;

    // lt fragments (B operand): 2 row-tiles x 4 k-steps
    bf16x8 lb[2][4];
    #pragma unroll
    for (int mr = 0; mr < 2; ++mr)
        #pragma unroll
        for (int ks = 0; ks < 4; ++ks)
            lb[mr][ks] = ld_bf8(ltb + (size_t)(mr * 16 + r0) * A_ + ks * 32 + g * 8);

    f32x4 zero = {0.f, 0.f, 0.f, 0.f};
    f32x4 acc[8][2];                                  // [col-tile][row-tile]
    #pragma unroll
    for (int c = 0; c < 8; ++c) { acc[c][0] = zero; acc[c][1] = zero; }

    #pragma unroll
    for (int c = 0; c < 8; ++c) {
        const unsigned short* rp = rtb + (size_t)(cb + c * 16 + r0) * A_;
        #pragma unroll
        for (int ks = 0; ks < 4; ++ks) {
            bf16x8 ra = ld_bf8(rp + ks * 32 + g * 8);   // rt rows = out cols (A operand)
            acc[c][0] = __builtin_amdgcn_mfma_f32_16x16x32_bf16(ra, lb[0][ks], acc[c][0], 0, 0, 0);
            acc[c][1] = __builtin_amdgcn_mfma_f32_16x16x32_bf16(ra, lb[1][ks], acc[c][1], 0, 0, 0);
        }
    }

    // masks: mask_rt as float4 per col-tile (cols cb+c*16+4g..+3), mask_lt per row
    float mlt[2];
    #pragma unroll
    for (int mr = 0; mr < 2; ++mr)
        mlt[mr] = mask_lt[(size_t)b * LLT + m0 + mr * 16 + r0];

    // exp (no max pass: |logit| <= ~20, clamp for safety) + per-row sums.
    // Fold mask_rt into stored P so mrt regs die before the store phase.
    __shared__ float red_sum[8][32];
    float rsum[2];
    #pragma unroll
    for (int mr = 0; mr < 2; ++mr) rsum[mr] = 0.f;

    #pragma unroll
    for (int c = 0; c < 8; ++c) {
        f32x4 m4 = *reinterpret_cast<const f32x4*>(mask_rt + (size_t)b * LRT + cb + c * 16 + 4 * g);
        #pragma unroll
        for (int mr = 0; mr < 2; ++mr)
            #pragma unroll
            for (int r = 0; r < 4; ++r) {
                float v = acc[c][mr][r] * (mlt[mr] * m4[r]);
                float e = __expf(fminf(v, 60.f));
                acc[c][mr][r] = e * m4[r];            // post-softmax rt-mask folded in
                rsum[mr] += e;
            }
    }
    #pragma unroll
    for (int mr = 0; mr < 2; ++mr) {
        float s = rsum[mr];
        s += __shfl_xor(s, 16, 64);
        s += __shfl_xor(s, 32, 64);
        rsum[mr] = s;
    }
    if (g == 0) {
        red_sum[wave][r0]      = rsum[0];
        red_sum[wave][16 + r0] = rsum[1];
    }
    __syncthreads();
    float sc[2];
    #pragma unroll
    for (int mr = 0; mr < 2; ++mr) {
        int rl = mr * 16 + r0;
        float s = red_sum[0][rl];
        #pragma unroll
        for (int w = 1; w < 8; ++w) s += red_sum[w][rl];
        sc[mr] = mlt[mr] * __builtin_amdgcn_rcpf(s);  // post-softmax lt-mask folded in
    }

    // store: float4 per (c, mr), through L2 (write-combining into full lines)
    #pragma unroll
    for (int mr = 0; mr < 2; ++mr) {
        float* op = out + ((size_t)b * LLT + m0 + mr * 16 + r0) * LRT + cb;
        #pragma unroll
        for (int c = 0; c < 8; ++c) {
            f32x4 o;
            #pragma unroll
            for (int r = 0; r < 4; ++r) o[r] = acc[c][mr][r] * sc[mr];
            *reinterpret_cast<f32x4*>(op + c * 16 + 4 * g) = o;
        }
    }
}

// ---------------------------------------------------------------------------
extern "C" void kernel_launch(void* const* d_in, const int* in_sizes, int n_in,
                              void* d_out, int out_size, void* d_ws, size_t ws_size,
                              hipStream_t stream) {
    const float* reps_lt = (const float*)d_in[0];
    const float* reps_rt = (const float*)d_in[1];
    const float* mask_lt = (const float*)d_in[2];
    const float* mask_rt = (const float*)d_in[3];
    const float* attn_k  = (const float*)d_in[4];
    const float* diagW   = (const float*)d_in[5];
    float* out = (float*)d_out;

    // workspace layout (bf16 as ushort bits)
    unsigned short* Kt  = (unsigned short*)d_ws;                // [A][H]   64 KB
    unsigned short* ltb = Kt + (size_t)A_ * H_;                 // [B*LLT][A]  8 MB
    unsigned short* rtb = ltb + (size_t)B_ * LLT * A_;          // [B*LRT][A]  8 MB

    k_prep<<<dim3((A_ * H_) / 256), dim3(256), 0, stream>>>(attn_k, Kt);
    k_proj<<<dim3((B_ * LLT) / 128, 2), dim3(256), 0, stream>>>(
        reps_lt, reps_rt, Kt, diagW, ltb, rtb);
    k_attn<<<dim3(LLT / 32 * B_), dim3(512), 0, stream>>>(
        ltb, rtb, mask_lt, mask_rt, out);
}

// Round 5
// 93.705 us; speedup vs baseline: 1.2630x; 1.1413x over previous
//
#include <hip/hip_runtime.h>
#include <hip/hip_bf16.h>

// Problem constants
#define B_   32
#define LLT  1024
#define LRT  1024
#define H_   256
#define A_   128

typedef __attribute__((ext_vector_type(8))) short  short8;
typedef __attribute__((ext_vector_type(4))) short  short4v;
typedef __attribute__((ext_vector_type(4))) float  f32x4;
typedef __bf16 bf16x8 __attribute__((ext_vector_type(8)));

static __device__ __forceinline__ unsigned short f2bf(float f) {
    return __builtin_bit_cast(unsigned short, (__bf16)f);   // native cvt, RNE
}

static __device__ __forceinline__ bf16x8 ld_bf8(const unsigned short* p) {
    return __builtin_bit_cast(bf16x8, *reinterpret_cast<const short8*>(p));
}

// fast tanh: (e^2x - 1) / (e^2x + 1); rel err ~1e-6, far below bf16 rounding
static __device__ __forceinline__ float fast_tanh(float x) {
    float cx = fminf(fmaxf(x, -15.f), 15.f);
    float e  = __expf(2.f * cx);
    return (e - 1.f) * __builtin_amdgcn_rcpf(e + 1.f);
}

// ---------------------------------------------------------------------------
// Kernel 0: attn_kernel [H][A] f32  ->  Kt [A][H] bf16 (transposed for frags)
// ---------------------------------------------------------------------------
__global__ void k_prep(const float* __restrict__ K, unsigned short* __restrict__ Kt) {
    int i = blockIdx.x * 256 + threadIdx.x;       // i in [0, A_*H_)
    int a = i >> 8;                               // / H_
    int h = i & (H_ - 1);
    Kt[i] = f2bf(K[h * A_ + a]);
}

// ---------------------------------------------------------------------------
// Kernel A: projection  [32768,256] @ [256,128] -> tanh -> (*diagW) -> bf16
// grid (256, 2): x = 128-row tile, y = {lt, rt}. block = 256 (4 waves).
// reps staged through LDS: global loads are 1KB-contiguous per instruction
// (2 rows x 32 lanes x 32B), converted to bf16 in regs, ds_write_b128 into
// slot = (kb + 4*row) mod 32  (addition swizzle: frag reads are 2-way = free).
// SWAPPED MFMA: A = Kt fragment (proj cols), B = reps fragment (proj rows)
// => C: lane&15 = proj ROW, reg = 4 consecutive proj COLS -> short4 stores.
// ---------------------------------------------------------------------------
__global__ __launch_bounds__(256) void k_proj(
        const float* __restrict__ reps_lt, const float* __restrict__ reps_rt,
        const unsigned short* __restrict__ Kt, const float* __restrict__ dW,
        unsigned short* __restrict__ lt_bf, unsigned short* __restrict__ rt_bf) {
    const bool is_lt = (blockIdx.y == 0);
    const float* __restrict__ src = is_lt ? reps_lt : reps_rt;
    unsigned short* __restrict__ dst = is_lt ? lt_bf : rt_bf;

    const int tid  = threadIdx.x;
    const int wave = tid >> 6, lane = tid & 63;
    const int g = lane >> 4, r0 = lane & 15;
    const int blockRow0 = blockIdx.x * 128;

    __shared__ unsigned short T[128 * 256];       // bf16 tile, 64 KB, swizzled slots

    // ---- stage: wave w covers rows w*32 .. w*32+31, 2 rows / iteration ----
    const int kb   = lane & 31;                   // slot (8 bf16 = 16 B) within row
    const int rsel = lane >> 5;                   // 0..1
    #pragma unroll 4
    for (int it = 0; it < 16; ++it) {
        int row_l = wave * 32 + it * 2 + rsel;
        const float* p = src + (size_t)(blockRow0 + row_l) * H_ + kb * 8;
        float4 x0 = *reinterpret_cast<const float4*>(p);
        float4 x1 = *reinterpret_cast<const float4*>(p + 4);
        short8 t;
        t[0] = (short)f2bf(x0.x); t[1] = (short)f2bf(x0.y);
        t[2] = (short)f2bf(x0.z); t[3] = (short)f2bf(x0.w);
        t[4] = (short)f2bf(x1.x); t[5] = (short)f2bf(x1.y);
        t[6] = (short)f2bf(x1.z); t[7] = (short)f2bf(x1.w);
        int s = (kb + 4 * row_l) & 31;
        *reinterpret_cast<short8*>(&T[row_l * 256 + s * 8]) = t;
    }
    __syncthreads();

    // ---- compute: wave w owns rows w*32..w*32+31 ----
    f32x4 zero = {0.f, 0.f, 0.f, 0.f};
    f32x4 acc[8][2];                              // [col-tile][row-tile]
    #pragma unroll
    for (int c = 0; c < 8; ++c) { acc[c][0] = zero; acc[c][1] = zero; }

    #pragma unroll
    for (int ks = 0; ks < 8; ++ks) {
        bf16x8 br[2];                             // reps rows (B operand) from LDS
        #pragma unroll
        for (int mr = 0; mr < 2; ++mr) {
            int row_l = wave * 32 + mr * 16 + r0;
            int s = (4 * ks + g + 4 * row_l) & 31;
            br[mr] = ld_bf8(&T[row_l * 256 + s * 8]);
        }
        #pragma unroll
        for (int c = 0; c < 8; ++c) {
            bf16x8 ka = ld_bf8(Kt + (size_t)(c * 16 + r0) * H_ + ks * 32 + g * 8);
            acc[c][0] = __builtin_amdgcn_mfma_f32_16x16x32_bf16(ka, br[0], acc[c][0], 0, 0, 0);
            acc[c][1] = __builtin_amdgcn_mfma_f32_16x16x32_bf16(ka, br[1], acc[c][1], 0, 0, 0);
        }
    }

    #pragma unroll
    for (int c = 0; c < 8; ++c) {
        f32x4 w4;
        if (is_lt) w4 = *reinterpret_cast<const f32x4*>(dW + c * 16 + 4 * g);
        else       { w4[0] = 1.f; w4[1] = 1.f; w4[2] = 1.f; w4[3] = 1.f; }
        #pragma unroll
        for (int mr = 0; mr < 2; ++mr) {
            int row = blockRow0 + wave * 32 + mr * 16 + r0;   // lane&15 = row
            short4v o;
            #pragma unroll
            for (int r = 0; r < 4; ++r)
                o[r] = (short)f2bf(fast_tanh(acc[c][mr][r]) * w4[r]);
            *reinterpret_cast<short4v*>(dst + (size_t)row * A_ + c * 16 + 4 * g) = o;
        }
    }
}

// ---------------------------------------------------------------------------
// Kernel B: per (batch, 32-row tile): S = lt·rt^T (K=128), masks, softmax.
// grid 1024 (XCD-grouped). block = 512 (8 waves, 128 cols each).
// SWAPPED MFMA => lane&15 = out ROW, reg = 4 consecutive out COLS.
// Epilogue: scaled P round-trips through a 16x1024 f32 LDS half-tile
// (slot = (col16 + 4*row) mod 256), then each wave streams full 4-KB rows
// as 1-KB-contiguous NT stores (fill-kernel-shaped write stream).
// ---------------------------------------------------------------------------
__global__ __launch_bounds__(512) void k_attn(
        const unsigned short* __restrict__ lt_bf, const unsigned short* __restrict__ rt_bf,
        const float* __restrict__ mask_lt, const float* __restrict__ mask_rt,
        float* __restrict__ out) {
    // XCD-aware decode: XCD = blk%8 (heuristic); XCD x serves batches 4x..4x+3.
    const int blk = blockIdx.x;
    const int b   = (blk & 7) * 4 + ((blk >> 3) & 3);
    const int m0  = (blk >> 5) * 32;

    const int tid = threadIdx.x;
    const int wave = tid >> 6, lane = tid & 63;
    const int g = lane >> 4, r0 = lane & 15;
    const int cb = wave * 128;

    __shared__ float P_lds[16 * 1024];            // 64 KB: one 16-row half
    __shared__ float red_sum[8][32];

    const unsigned short* __restrict__ ltb = lt_bf + ((size_t)b * LLT + m0) * A_;
    const unsigned short* __restrict__ rtb = rt_bf + (size_t)b * LRT * A_;

    // lt fragments (B operand): 2 row-tiles x 4 k-steps
    bf16x8 lb[2][4];
    #pragma unroll
    for (int mr = 0; mr < 2; ++mr)
        #pragma unroll
        for (int ks = 0; ks < 4; ++ks)
            lb[mr][ks] = ld_bf8(ltb + (size_t)(mr * 16 + r0) * A_ + ks * 32 + g * 8);

    f32x4 zero = {0.f, 0.f, 0.f, 0.f};
    f32x4 acc[8][2];                              // [col-tile][row-tile]
    #pragma unroll
    for (int c = 0; c < 8; ++c) { acc[c][0] = zero; acc[c][1] = zero; }

    #pragma unroll
    for (int c = 0; c < 8; ++c) {
        const unsigned short* rp = rtb + (size_t)(cb + c * 16 + r0) * A_;
        #pragma unroll
        for (int ks = 0; ks < 4; ++ks) {
            bf16x8 ra = ld_bf8(rp + ks * 32 + g * 8);   // rt rows = out cols (A op)
            acc[c][0] = __builtin_amdgcn_mfma_f32_16x16x32_bf16(ra, lb[0][ks], acc[c][0], 0, 0, 0);
            acc[c][1] = __builtin_amdgcn_mfma_f32_16x16x32_bf16(ra, lb[1][ks], acc[c][1], 0, 0, 0);
        }
    }

    // masks
    float mlt[2];
    #pragma unroll
    for (int mr = 0; mr < 2; ++mr)
        mlt[mr] = mask_lt[(size_t)b * LLT + m0 + mr * 16 + r0];

    // exp (no max pass: logits bounded by tanh outputs; clamp for safety) + sums
    float rsum[2];
    rsum[0] = 0.f; rsum[1] = 0.f;
    #pragma unroll
    for (int c = 0; c < 8; ++c) {
        f32x4 m4 = *reinterpret_cast<const f32x4*>(mask_rt + (size_t)b * LRT + cb + c * 16 + 4 * g);
        #pragma unroll
        for (int mr = 0; mr < 2; ++mr)
            #pragma unroll
            for (int r = 0; r < 4; ++r) {
                float v = acc[c][mr][r] * (mlt[mr] * m4[r]);
                float e = __expf(fminf(v, 60.f));
                acc[c][mr][r] = e * m4[r];        // post-softmax rt-mask folded in
                rsum[mr] += e;
            }
    }
    #pragma unroll
    for (int mr = 0; mr < 2; ++mr) {
        float s = rsum[mr];
        s += __shfl_xor(s, 16, 64);
        s += __shfl_xor(s, 32, 64);
        rsum[mr] = s;
    }
    if (g == 0) {
        red_sum[wave][r0]      = rsum[0];
        red_sum[wave][16 + r0] = rsum[1];
    }
    __syncthreads();
    float sc[2];
    #pragma unroll
    for (int mr = 0; mr < 2; ++mr) {
        int rl = mr * 16 + r0;
        float s = red_sum[0][rl];
        #pragma unroll
        for (int w = 1; w < 8; ++w) s += red_sum[w][rl];
        sc[mr] = mlt[mr] * __builtin_amdgcn_rcpf(s);  // post-softmax lt-mask folded in
    }

    // epilogue: per 16-row half, transpose via LDS then stream contiguous rows
    #pragma unroll
    for (int mr = 0; mr < 2; ++mr) {
        // write scaled P: rows r0, col granule (16B) = (col16 + 4*row) & 255
        #pragma unroll
        for (int c = 0; c < 8; ++c) {
            f32x4 o;
            #pragma unroll
            for (int r = 0; r < 4; ++r) o[r] = acc[c][mr][r] * sc[mr];
            int col16 = wave * 32 + 4 * c + g;            // natural granule 0..255
            int gran  = (col16 + 4 * r0) & 255;
            *reinterpret_cast<f32x4*>(&P_lds[r0 * 1024 + gran * 4]) = o;
        }
        __syncthreads();
        // read + store: wave handles local rows 2*wave, 2*wave+1 (1 KB/instr)
        #pragma unroll
        for (int i = 0; i < 2; ++i) {
            int row_l = 2 * wave + i;
            float* op = out + ((size_t)b * LLT + m0 + mr * 16 + row_l) * LRT;
            #pragma unroll
            for (int seg = 0; seg < 4; ++seg) {
                int gran = (lane + 64 * seg + 4 * row_l) & 255;
                f32x4 v = *reinterpret_cast<const f32x4*>(&P_lds[row_l * 1024 + gran * 4]);
                __builtin_nontemporal_store(v, reinterpret_cast<f32x4*>(op + seg * 256 + lane * 4));
            }
        }
        __syncthreads();
    }
}

// ---------------------------------------------------------------------------
extern "C" void kernel_launch(void* const* d_in, const int* in_sizes, int n_in,
                              void* d_out, int out_size, void* d_ws, size_t ws_size,
                              hipStream_t stream) {
    const float* reps_lt = (const float*)d_in[0];
    const float* reps_rt = (const float*)d_in[1];
    const float* mask_lt = (const float*)d_in[2];
    const float* mask_rt = (const float*)d_in[3];
    const float* attn_k  = (const float*)d_in[4];
    const float* diagW   = (const float*)d_in[5];
    float* out = (float*)d_out;

    // workspace layout (bf16 as ushort bits)
    unsigned short* Kt  = (unsigned short*)d_ws;                // [A][H]   64 KB
    unsigned short* ltb = Kt + (size_t)A_ * H_;                 // [B*LLT][A]  8 MB
    unsigned short* rtb = ltb + (size_t)B_ * LLT * A_;          // [B*LRT][A]  8 MB

    k_prep<<<dim3((A_ * H_) / 256), dim3(256), 0, stream>>>(attn_k, Kt);
    k_proj<<<dim3((B_ * LLT) / 128, 2), dim3(256), 0, stream>>>(
        reps_lt, reps_rt, Kt, diagW, ltb, rtb);
    k_attn<<<dim3(LLT / 32 * B_), dim3(512), 0, stream>>>(
        ltb, rtb, mask_lt, mask_rt, out);
}